// Round 1
// baseline (12775.668 us; speedup 1.0000x reference)
//
#include <hip/hip_runtime.h>
#include <math.h>

// GRU seq2seq: 2-layer encoder (T=30) + autoregressive decoder (T=60), B=4096, H=512.
// Round 0: exact-fp32 baseline. 150 sequential GEMMs M=4096,N=1536,K=512 (~966 GF)
// + fused elementwise GRU kernels. MFMA conversion planned once correctness anchored.

#define B_SZ  4096
#define H     512
#define H3    1536
#define TOBS  30
#define TPRED 60

#define BM 128
#define BN 128
#define BK 16

// C[ksplit][M x H3] = A[M x H] @ W[H3 x H]^T   (split-K=2, halves summed in elementwise)
// blockIdx.z: bit0 = k-split, bit1 = which (A0/W0/C0 vs A1/W1/C1) for dual-GEMM launches.
__global__ __launch_bounds__(256)
void gemm_htw(const float* __restrict__ A0, const float* __restrict__ W0, float* __restrict__ C0,
              const float* __restrict__ A1, const float* __restrict__ W1, float* __restrict__ C1)
{
    const int which = blockIdx.z >> 1;
    const int ks    = blockIdx.z & 1;
    const float* A = which ? A1 : A0;
    const float* W = which ? W1 : W0;
    float*       C = (which ? C1 : C0) + (size_t)ks * B_SZ * H3;

    __shared__ float As[BK][BM + 4];   // transposed: As[k][m]
    __shared__ float Ws[BK][BN + 4];   // transposed: Ws[k][n]

    const int tid = threadIdx.x;
    const int tx  = tid & 15;          // n-group
    const int ty  = tid >> 4;          // m-group
    const int m0  = blockIdx.y * BM;
    const int n0  = blockIdx.x * BN;
    const int lr  = tid >> 2;          // 0..63: tile row for staging
    const int lq  = tid & 3;           // float4 slot in k

    float acc[2][2][4][4];
#pragma unroll
    for (int a = 0; a < 2; ++a)
#pragma unroll
        for (int b = 0; b < 2; ++b)
#pragma unroll
            for (int i = 0; i < 4; ++i)
#pragma unroll
                for (int j = 0; j < 4; ++j) acc[a][b][i][j] = 0.f;

    const int kbase = ks * (H / 2);
    for (int k0 = kbase; k0 < kbase + H / 2; k0 += BK) {
#pragma unroll
        for (int half = 0; half < 2; ++half) {
            int r = lr + half * 64;
            float4 av = *(const float4*)(A + (size_t)(m0 + r) * H + k0 + lq * 4);
            float4 wv = *(const float4*)(W + (size_t)(n0 + r) * H + k0 + lq * 4);
            As[lq*4+0][r] = av.x; As[lq*4+1][r] = av.y; As[lq*4+2][r] = av.z; As[lq*4+3][r] = av.w;
            Ws[lq*4+0][r] = wv.x; Ws[lq*4+1][r] = wv.y; Ws[lq*4+2][r] = wv.z; Ws[lq*4+3][r] = wv.w;
        }
        __syncthreads();
#pragma unroll
        for (int k = 0; k < BK; ++k) {
            float4 a0 = *(const float4*)&As[k][ty * 4];
            float4 a1 = *(const float4*)&As[k][64 + ty * 4];
            float4 b0 = *(const float4*)&Ws[k][tx * 4];
            float4 b1 = *(const float4*)&Ws[k][64 + tx * 4];
            float ar[2][4] = {{a0.x,a0.y,a0.z,a0.w},{a1.x,a1.y,a1.z,a1.w}};
            float br[2][4] = {{b0.x,b0.y,b0.z,b0.w},{b1.x,b1.y,b1.z,b1.w}};
#pragma unroll
            for (int ai = 0; ai < 2; ++ai)
#pragma unroll
                for (int bi = 0; bi < 2; ++bi)
#pragma unroll
                    for (int i = 0; i < 4; ++i)
#pragma unroll
                        for (int j = 0; j < 4; ++j)
                            acc[ai][bi][i][j] += ar[ai][i] * br[bi][j];
        }
        __syncthreads();
    }

#pragma unroll
    for (int ai = 0; ai < 2; ++ai)
#pragma unroll
        for (int i = 0; i < 4; ++i) {
            int row = m0 + ai * 64 + ty * 4 + i;
#pragma unroll
            for (int bi = 0; bi < 2; ++bi) {
                float4 v = make_float4(acc[ai][bi][i][0], acc[ai][bi][i][1],
                                       acc[ai][bi][i][2], acc[ai][bi][i][3]);
                *(float4*)(C + (size_t)row * H3 + n0 + bi * 64 + tx * 4) = v;
            }
        }
}

__global__ void init_state(const float* __restrict__ x, float* __restrict__ h0,
                           float* __restrict__ h1, float* __restrict__ din)
{
    int idx = blockIdx.x * blockDim.x + threadIdx.x;
    if (idx < B_SZ * H) { h0[idx] = 0.f; h1[idx] = 0.f; }
    if (idx < B_SZ * 2) din[idx] = x[(size_t)(idx >> 1) * (TOBS * 4) + 29 * 4 + (idx & 1)];
}

__device__ __forceinline__ float sigmoidf_(float v) { return 1.f / (1.f + expf(-v)); }

// Layer-0 cell: gi (K=4) computed inline from x[:,t,:]; gh from split-K buffer.
__global__ void gru_l0(const float* __restrict__ x, int t,
                       const float* __restrict__ Wih, const float* __restrict__ bih,
                       const float* __restrict__ bhh,
                       const float* __restrict__ gh, float* __restrict__ h)
{
    int idx = blockIdx.x * blockDim.x + threadIdx.x;
    int b = idx >> 9, j = idx & (H - 1);
    const float* xb = x + (size_t)b * (TOBS * 4) + t * 4;
    float x0 = xb[0], x1 = xb[1], x2 = xb[2], x3 = xb[3];
    const float* w0 = Wih + (size_t)j * 4;
    const float* w1 = Wih + (size_t)(H + j) * 4;
    const float* w2 = Wih + (size_t)(2 * H + j) * 4;
    float gir = bih[j]       + x0*w0[0] + x1*w0[1] + x2*w0[2] + x3*w0[3];
    float giz = bih[H+j]     + x0*w1[0] + x1*w1[1] + x2*w1[2] + x3*w1[3];
    float gin = bih[2*H+j]   + x0*w2[0] + x1*w2[1] + x2*w2[2] + x3*w2[3];
    size_t base = (size_t)b * H3;
    size_t off  = (size_t)B_SZ * H3;
    float ghr = gh[base + j]         + gh[base + off + j]         + bhh[j];
    float ghz = gh[base + H + j]     + gh[base + off + H + j]     + bhh[H + j];
    float ghn = gh[base + 2*H + j]   + gh[base + off + 2*H + j]   + bhh[2*H + j];
    float r = sigmoidf_(gir + ghr);
    float z = sigmoidf_(giz + ghz);
    float n = tanhf(gin + r * ghn);
    h[idx] = (1.f - z) * n + z * h[idx];
}

// Layer-1 cell: gi and gh both from split-K GEMM buffers.
__global__ void gru_l1(const float* __restrict__ gi, const float* __restrict__ gh,
                       const float* __restrict__ bih, const float* __restrict__ bhh,
                       float* __restrict__ h)
{
    int idx = blockIdx.x * blockDim.x + threadIdx.x;
    int b = idx >> 9, j = idx & (H - 1);
    size_t base = (size_t)b * H3;
    size_t off  = (size_t)B_SZ * H3;
    float gir = gi[base + j]       + gi[base + off + j]       + bih[j];
    float giz = gi[base + H + j]   + gi[base + off + H + j]   + bih[H + j];
    float gin = gi[base + 2*H + j] + gi[base + off + 2*H + j] + bih[2*H + j];
    float ghr = gh[base + j]       + gh[base + off + j]       + bhh[j];
    float ghz = gh[base + H + j]   + gh[base + off + H + j]   + bhh[H + j];
    float ghn = gh[base + 2*H + j] + gh[base + off + 2*H + j] + bhh[2*H + j];
    float r = sigmoidf_(gir + ghr);
    float z = sigmoidf_(giz + ghz);
    float n = tanhf(gin + r * ghn);
    h[idx] = (1.f - z) * n + z * h[idx];
}

// Decoder cell + FC head. One block per batch row; 512 threads = hidden units.
// din is read by all threads before the barrier, rewritten by thread 0 after -> in-place safe.
__global__ __launch_bounds__(512)
void gru_dec(float* __restrict__ din, const float* __restrict__ Wih,
             const float* __restrict__ bih, const float* __restrict__ bhh,
             const float* __restrict__ gh, float* __restrict__ h,
             const float* __restrict__ Wfc, const float* __restrict__ bfc,
             float* __restrict__ out, int t)
{
    int b = blockIdx.x, j = threadIdx.x;
    float x0 = din[b * 2 + 0], x1 = din[b * 2 + 1];
    float gir = bih[j]       + x0 * Wih[(size_t)j * 2]           + x1 * Wih[(size_t)j * 2 + 1];
    float giz = bih[H + j]   + x0 * Wih[(size_t)(H + j) * 2]     + x1 * Wih[(size_t)(H + j) * 2 + 1];
    float gin = bih[2*H + j] + x0 * Wih[(size_t)(2*H + j) * 2]   + x1 * Wih[(size_t)(2*H + j) * 2 + 1];
    size_t base = (size_t)b * H3;
    size_t off  = (size_t)B_SZ * H3;
    float ghr = gh[base + j]       + gh[base + off + j]       + bhh[j];
    float ghz = gh[base + H + j]   + gh[base + off + H + j]   + bhh[H + j];
    float ghn = gh[base + 2*H + j] + gh[base + off + 2*H + j] + bhh[2*H + j];
    float r = sigmoidf_(gir + ghr);
    float z = sigmoidf_(giz + ghz);
    float n = tanhf(gin + r * ghn);
    float hn = (1.f - z) * n + z * h[(size_t)b * H + j];
    h[(size_t)b * H + j] = hn;

    float v0 = hn * Wfc[j];
    float v1 = hn * Wfc[H + j];
#pragma unroll
    for (int m = 32; m; m >>= 1) { v0 += __shfl_xor(v0, m); v1 += __shfl_xor(v1, m); }
    __shared__ float red0[8], red1[8];
    int wv = j >> 6, ln = j & 63;
    if (ln == 0) { red0[wv] = v0; red1[wv] = v1; }
    __syncthreads();
    if (j == 0) {
        float p0 = bfc[0], p1 = bfc[1];
#pragma unroll
        for (int w = 0; w < 8; ++w) { p0 += red0[w]; p1 += red1[w]; }
        out[(size_t)b * (TPRED * 2) + t * 2 + 0] = p0;
        out[(size_t)b * (TPRED * 2) + t * 2 + 1] = p1;
        din[b * 2 + 0] = p0;
        din[b * 2 + 1] = p1;
    }
}

extern "C" void kernel_launch(void* const* d_in, const int* in_sizes, int n_in,
                              void* d_out, int out_size, void* d_ws, size_t ws_size,
                              hipStream_t stream)
{
    const float* x    = (const float*)d_in[0];
    const float* Wih0 = (const float*)d_in[1];
    const float* Whh0 = (const float*)d_in[2];
    const float* bih0 = (const float*)d_in[3];
    const float* bhh0 = (const float*)d_in[4];
    const float* Wih1 = (const float*)d_in[5];
    const float* Whh1 = (const float*)d_in[6];
    const float* bih1 = (const float*)d_in[7];
    const float* bhh1 = (const float*)d_in[8];
    const float* Wihd = (const float*)d_in[9];
    const float* Whhd = (const float*)d_in[10];
    const float* bihd = (const float*)d_in[11];
    const float* bhhd = (const float*)d_in[12];
    const float* Wfc  = (const float*)d_in[13];
    const float* bfc  = (const float*)d_in[14];
    float* out = (float*)d_out;

    // workspace: h0(BH) | h1(BH) | g0(2*B*H3) | g1(2*B*H3) | din(2B)  ~= 118 MB fp32
    float* p  = (float*)d_ws;
    float* h0 = p;  p += (size_t)B_SZ * H;
    float* h1 = p;  p += (size_t)B_SZ * H;
    float* g0 = p;  p += 2 * (size_t)B_SZ * H3;
    float* g1 = p;  p += 2 * (size_t)B_SZ * H3;
    float* din = p;

    dim3 blk(256);
    dim3 grid1(H3 / BN, B_SZ / BM, 2);  // one GEMM, split-K=2
    dim3 grid2(H3 / BN, B_SZ / BM, 4);  // dual GEMM (gi1 + gh1), split-K=2 each
    int ew_blocks = (B_SZ * H) / 256;

    init_state<<<ew_blocks, 256, 0, stream>>>(x, h0, h1, din);

    for (int t = 0; t < TOBS; ++t) {
        // gh0 = h0 @ Whh0^T
        gemm_htw<<<grid1, blk, 0, stream>>>(h0, Whh0, g0, h0, Whh0, g0);
        gru_l0<<<ew_blocks, 256, 0, stream>>>(x, t, Wih0, bih0, bhh0, g0, h0);
        // gi1 = h0_new @ Wih1^T ; gh1 = h1 @ Whh1^T
        gemm_htw<<<grid2, blk, 0, stream>>>(h0, Wih1, g0, h1, Whh1, g1);
        gru_l1<<<ew_blocks, 256, 0, stream>>>(g0, g1, bih1, bhh1, h1);
    }
    for (int t = 0; t < TPRED; ++t) {
        // ghd = h1 @ Whhd^T   (h1 doubles as decoder state after encoder)
        gemm_htw<<<grid1, blk, 0, stream>>>(h1, Whhd, g0, h1, Whhd, g0);
        gru_dec<<<B_SZ, 512, 0, stream>>>(din, Wihd, bihd, bhhd, g0, h1, Wfc, bfc, out, t);
    }
}

// Round 2
// 5011.507 us; speedup vs baseline: 2.5493x; 2.5493x over previous
//
#include <hip/hip_runtime.h>
#include <math.h>

// GRU seq2seq on MI355X. Round 1: split-bf16 (hi+lo) 3-term MFMA GEMM, fp32-equivalent
// accuracy. 150 sequential GEMMs M=4096,N=1536,K=512(x3 terms). m97-style staging:
// global_load_lds w16, pre-swizzled source chunks, 128x64 tiles (768 blocks = 3/CU).

#define B_SZ  4096
#define H     512
#define H3    1536
#define TOBS  30
#define TPRED 60

typedef float f32x4 __attribute__((ext_vector_type(4)));
typedef short s16x8 __attribute__((ext_vector_type(8)));
typedef __bf16 bf16x8 __attribute__((ext_vector_type(8)));

__device__ __forceinline__ float b2f(unsigned short u) {
    unsigned v = (unsigned)u << 16; return __builtin_bit_cast(float, v);
}
__device__ __forceinline__ unsigned short f2b(float f) {  // RNE
    unsigned u = __builtin_bit_cast(unsigned, f);
    return (unsigned short)((u + 0x7FFF + ((u >> 16) & 1)) >> 16);
}

typedef __attribute__((address_space(1))) void gvoid;
typedef __attribute__((address_space(3))) void lvoid;
__device__ __forceinline__ void gl16(const void* g, void* l) {
    __builtin_amdgcn_global_load_lds((gvoid*)g, (lvoid*)l, 16, 0, 0);
}

__device__ __forceinline__ f32x4 mfma_bf16(s16x8 a, s16x8 b, f32x4 c) {
    return __builtin_amdgcn_mfma_f32_16x16x32_bf16(
        __builtin_bit_cast(bf16x8, a), __builtin_bit_cast(bf16x8, b), c, 0, 0, 0);
}

struct GemmOps {
    const unsigned short* Ah[2]; const unsigned short* Al[2];
    const unsigned short* Wh[2]; const unsigned short* Wl[2];
    float* C[2];
};

// C[m][n] = sum_k (Ah+Al)[m][k]*(Wh+Wl)[n][k], 3-term split-bf16, fp32 accum.
// Tile 128(m) x 64(n), BK=32, 256 threads = 4 waves (2x2), wave out 64x32.
// grid.x = 768 flattened (24 n-tiles x 32 m-tiles), XCD-chunk swizzled; grid.z selects operand set.
__global__ __launch_bounds__(256)
void gemm3(GemmOps ops)
{
    const int z = blockIdx.z;
    const unsigned short* __restrict__ Ah = ops.Ah[z];
    const unsigned short* __restrict__ Al = ops.Al[z];
    const unsigned short* __restrict__ Wh = ops.Wh[z];
    const unsigned short* __restrict__ Wl = ops.Wl[z];
    float* __restrict__ C = ops.C[z];

    // XCD-aware bijective swizzle: 768 blocks, 8 XCDs, 96 contiguous tiles per XCD.
    int bid = (int)blockIdx.x;
    int swz = (bid & 7) * 96 + (bid >> 3);
    const int n0 = (swz % 24) * 64;
    const int m0 = (swz / 24) * 128;

    __shared__ unsigned short sAh[128 * 32], sAl[128 * 32];
    __shared__ unsigned short sWh[64 * 32],  sWl[64 * 32];

    const int tid  = threadIdx.x;
    const int w    = tid >> 6;
    const int lane = tid & 63;
    const int wr = w >> 1, wc = w & 1;     // wave grid 2x2
    const int q  = lane >> 4;              // k-chunk selector (0..3)
    const int lr = lane & 15;

    f32x4 acc[4][2];
#pragma unroll
    for (int i = 0; i < 4; ++i)
#pragma unroll
        for (int j = 0; j < 2; ++j) acc[i][j] = (f32x4){0.f, 0.f, 0.f, 0.f};

    const int wbase = (tid & ~63);         // wave-uniform slot base

    for (int k0 = 0; k0 < H; k0 += 32) {
        // Stage A (128x32) hi+lo: 2 instrs each. Slot i covers 16B: row=i>>2, pos=i&3.
        // LDS is linear in slot order; global chunk fetched = pos ^ ((row>>1)&3)  (swizzle).
#pragma unroll
        for (int s = 0; s < 2; ++s) {
            int i = s * 256 + tid;
            int row = i >> 2, p = i & 3;
            int c = p ^ ((row >> 1) & 3);
            size_t goff = (size_t)(m0 + row) * H + k0 + c * 8;
            gl16(Ah + goff, &sAh[(s * 256 + wbase) * 8]);
            gl16(Al + goff, &sAl[(s * 256 + wbase) * 8]);
        }
        {   // Stage W (64x32) hi+lo: 1 instr each.
            int i = tid;
            int row = i >> 2, p = i & 3;
            int c = p ^ ((row >> 1) & 3);
            size_t goff = (size_t)(n0 + row) * H + k0 + c * 8;
            gl16(Wh + goff, &sWh[wbase * 8]);
            gl16(Wl + goff, &sWl[wbase * 8]);
        }
        __syncthreads();

        s16x8 afh[4], afl[4], bfh[2], bfl[2];
#pragma unroll
        for (int fi = 0; fi < 4; ++fi) {
            int r = wr * 64 + fi * 16 + lr;
            int pos = q ^ ((r >> 1) & 3);
            afh[fi] = *(const s16x8*)&sAh[r * 32 + pos * 8];
            afl[fi] = *(const s16x8*)&sAl[r * 32 + pos * 8];
        }
#pragma unroll
        for (int fj = 0; fj < 2; ++fj) {
            int r = wc * 32 + fj * 16 + lr;
            int pos = q ^ ((r >> 1) & 3);
            bfh[fj] = *(const s16x8*)&sWh[r * 32 + pos * 8];
            bfl[fj] = *(const s16x8*)&sWl[r * 32 + pos * 8];
        }
#pragma unroll
        for (int fi = 0; fi < 4; ++fi)
#pragma unroll
            for (int fj = 0; fj < 2; ++fj) {
                acc[fi][fj] = mfma_bf16(afh[fi], bfh[fj], acc[fi][fj]);  // hi*Hi
                acc[fi][fj] = mfma_bf16(afh[fi], bfl[fj], acc[fi][fj]);  // hi*Lo
                acc[fi][fj] = mfma_bf16(afl[fi], bfh[fj], acc[fi][fj]);  // lo*Hi
            }
        __syncthreads();
    }

    // C/D layout: col = lane&15, row = (lane>>4)*4 + reg  [m89]
#pragma unroll
    for (int fi = 0; fi < 4; ++fi)
#pragma unroll
        for (int fj = 0; fj < 2; ++fj) {
            int col  = n0 + wc * 32 + fj * 16 + lr;
            int rowb = m0 + wr * 64 + fi * 16 + q * 4;
#pragma unroll
            for (int j = 0; j < 4; ++j)
                C[(size_t)(rowb + j) * H3 + col] = acc[fi][fj][j];
        }
}

// Split 4 weight matrices (each H3 x H fp32) into bf16 hi/lo pairs.
__global__ void wprep(const float* __restrict__ s0, const float* __restrict__ s1,
                      const float* __restrict__ s2, const float* __restrict__ s3,
                      unsigned short* __restrict__ d)
{
    int m = blockIdx.y;
    const float* s = (m == 0) ? s0 : (m == 1) ? s1 : (m == 2) ? s2 : s3;
    unsigned short* dh = d + (size_t)m * 2 * H3 * H;
    unsigned short* dl = dh + (size_t)H3 * H;
    int i = blockIdx.x * 256 + threadIdx.x;
    float wv = s[i];
    unsigned short hi = f2b(wv);
    dh[i] = hi;
    dl[i] = f2b(wv - b2f(hi));
}

__global__ void init_state(const float* __restrict__ x,
                           unsigned short* __restrict__ h0h, unsigned short* __restrict__ h0l,
                           unsigned short* __restrict__ h1h, unsigned short* __restrict__ h1l,
                           float* __restrict__ din)
{
    int idx = blockIdx.x * blockDim.x + threadIdx.x;
    if (idx < B_SZ * H) { h0h[idx] = 0; h0l[idx] = 0; h1h[idx] = 0; h1l[idx] = 0; }
    if (idx < B_SZ * 2) din[idx] = x[(size_t)(idx >> 1) * (TOBS * 4) + 29 * 4 + (idx & 1)];
}

__device__ __forceinline__ float sigmoidf_(float v) { return 1.f / (1.f + expf(-v)); }
__device__ __forceinline__ void store_hl(unsigned short* hh, unsigned short* hl, int idx, float v) {
    unsigned short hi = f2b(v);
    hh[idx] = hi;
    hl[idx] = f2b(v - b2f(hi));
}

// Layer-0 cell: gi (K=4) inline from x; gh from GEMM buffer. h kept as bf16 hi/lo.
__global__ void gru_l0(const float* __restrict__ x, int t,
                       const float* __restrict__ Wih, const float* __restrict__ bih,
                       const float* __restrict__ bhh, const float* __restrict__ gh,
                       unsigned short* __restrict__ hh, unsigned short* __restrict__ hl)
{
    int idx = blockIdx.x * blockDim.x + threadIdx.x;
    int b = idx >> 9, j = idx & (H - 1);
    const float* xb = x + (size_t)b * (TOBS * 4) + t * 4;
    float x0 = xb[0], x1 = xb[1], x2 = xb[2], x3 = xb[3];
    const float* w0 = Wih + (size_t)j * 4;
    const float* w1 = Wih + (size_t)(H + j) * 4;
    const float* w2 = Wih + (size_t)(2 * H + j) * 4;
    float gir = bih[j]     + x0*w0[0] + x1*w0[1] + x2*w0[2] + x3*w0[3];
    float giz = bih[H+j]   + x0*w1[0] + x1*w1[1] + x2*w1[2] + x3*w1[3];
    float gin = bih[2*H+j] + x0*w2[0] + x1*w2[1] + x2*w2[2] + x3*w2[3];
    size_t base = (size_t)b * H3;
    float r = sigmoidf_(gir + gh[base + j]       + bhh[j]);
    float zg = sigmoidf_(giz + gh[base + H + j]   + bhh[H + j]);
    float n = tanhf(gin + r * (gh[base + 2*H + j] + bhh[2*H + j]));
    float h_old = b2f(hh[idx]) + b2f(hl[idx]);
    store_hl(hh, hl, idx, (1.f - zg) * n + zg * h_old);
}

// Layer-1 cell: gi and gh from GEMM buffers.
__global__ void gru_l1(const float* __restrict__ gi, const float* __restrict__ gh,
                       const float* __restrict__ bih, const float* __restrict__ bhh,
                       unsigned short* __restrict__ hh, unsigned short* __restrict__ hl)
{
    int idx = blockIdx.x * blockDim.x + threadIdx.x;
    int b = idx >> 9, j = idx & (H - 1);
    size_t base = (size_t)b * H3;
    float r = sigmoidf_(gi[base + j]       + bih[j]       + gh[base + j]       + bhh[j]);
    float zg = sigmoidf_(gi[base + H + j]   + bih[H + j]   + gh[base + H + j]   + bhh[H + j]);
    float n = tanhf(gi[base + 2*H + j] + bih[2*H + j]
                    + r * (gh[base + 2*H + j] + bhh[2*H + j]));
    float h_old = b2f(hh[idx]) + b2f(hl[idx]);
    store_hl(hh, hl, idx, (1.f - zg) * n + zg * h_old);
}

// Decoder cell + FC head. One block per batch row, 512 threads = hidden units.
__global__ __launch_bounds__(512)
void gru_dec(float* __restrict__ din, const float* __restrict__ Wih,
             const float* __restrict__ bih, const float* __restrict__ bhh,
             const float* __restrict__ gh,
             unsigned short* __restrict__ hh, unsigned short* __restrict__ hl,
             const float* __restrict__ Wfc, const float* __restrict__ bfc,
             float* __restrict__ out, int t)
{
    int b = blockIdx.x, j = threadIdx.x;
    float x0 = din[b * 2 + 0], x1 = din[b * 2 + 1];
    float gir = bih[j]       + x0 * Wih[(size_t)j * 2]         + x1 * Wih[(size_t)j * 2 + 1];
    float giz = bih[H + j]   + x0 * Wih[(size_t)(H + j) * 2]   + x1 * Wih[(size_t)(H + j) * 2 + 1];
    float gin = bih[2*H + j] + x0 * Wih[(size_t)(2*H + j) * 2] + x1 * Wih[(size_t)(2*H + j) * 2 + 1];
    size_t base = (size_t)b * H3;
    float r = sigmoidf_(gir + gh[base + j]       + bhh[j]);
    float zg = sigmoidf_(giz + gh[base + H + j]   + bhh[H + j]);
    float n = tanhf(gin + r * (gh[base + 2*H + j] + bhh[2*H + j]));
    int idx = b * H + j;
    float h_old = b2f(hh[idx]) + b2f(hl[idx]);
    float hn = (1.f - zg) * n + zg * h_old;
    store_hl(hh, hl, idx, hn);

    float v0 = hn * Wfc[j];
    float v1 = hn * Wfc[H + j];
#pragma unroll
    for (int m = 32; m; m >>= 1) { v0 += __shfl_xor(v0, m); v1 += __shfl_xor(v1, m); }
    __shared__ float red0[8], red1[8];
    int wv = j >> 6, ln = j & 63;
    if (ln == 0) { red0[wv] = v0; red1[wv] = v1; }
    __syncthreads();
    if (j == 0) {
        float p0 = bfc[0], p1 = bfc[1];
#pragma unroll
        for (int w = 0; w < 8; ++w) { p0 += red0[w]; p1 += red1[w]; }
        out[(size_t)b * (TPRED * 2) + t * 2 + 0] = p0;
        out[(size_t)b * (TPRED * 2) + t * 2 + 1] = p1;
        din[b * 2 + 0] = p0;
        din[b * 2 + 1] = p1;
    }
}

extern "C" void kernel_launch(void* const* d_in, const int* in_sizes, int n_in,
                              void* d_out, int out_size, void* d_ws, size_t ws_size,
                              hipStream_t stream)
{
    const float* x    = (const float*)d_in[0];
    const float* Wih0 = (const float*)d_in[1];
    const float* Whh0 = (const float*)d_in[2];
    const float* bih0 = (const float*)d_in[3];
    const float* bhh0 = (const float*)d_in[4];
    const float* Wih1 = (const float*)d_in[5];
    const float* Whh1 = (const float*)d_in[6];
    const float* bih1 = (const float*)d_in[7];
    const float* bhh1 = (const float*)d_in[8];
    const float* Wihd = (const float*)d_in[9];
    const float* Whhd = (const float*)d_in[10];
    const float* bihd = (const float*)d_in[11];
    const float* bhhd = (const float*)d_in[12];
    const float* Wfc  = (const float*)d_in[13];
    const float* bfc  = (const float*)d_in[14];
    float* out = (float*)d_out;

    // workspace: g0,g1 (B*H3 f32 each) | din (2B f32) | h0/h1 hi+lo (B*H u16 x4) | W splits
    char* p = (char*)d_ws;
    float* g0  = (float*)p;  p += (size_t)B_SZ * H3 * 4;
    float* g1  = (float*)p;  p += (size_t)B_SZ * H3 * 4;
    float* din = (float*)p;  p += (size_t)B_SZ * 2 * 4;
    unsigned short* h0h = (unsigned short*)p; p += (size_t)B_SZ * H * 2;
    unsigned short* h0l = (unsigned short*)p; p += (size_t)B_SZ * H * 2;
    unsigned short* h1h = (unsigned short*)p; p += (size_t)B_SZ * H * 2;
    unsigned short* h1l = (unsigned short*)p; p += (size_t)B_SZ * H * 2;
    unsigned short* wsp = (unsigned short*)p;  // 4 matrices x {hi,lo} x H3*H
    const size_t WM = (size_t)H3 * H;
    unsigned short *Whh0h = wsp + 0*2*WM, *Whh0l = wsp + 0*2*WM + WM;
    unsigned short *Wih1h = wsp + 1*2*WM, *Wih1l = wsp + 1*2*WM + WM;
    unsigned short *Whh1h = wsp + 2*2*WM, *Whh1l = wsp + 2*2*WM + WM;
    unsigned short *Whhdh = wsp + 3*2*WM, *Whhdl = wsp + 3*2*WM + WM;

    int ew_blocks = (B_SZ * H) / 256;
    wprep<<<dim3((H3 * H) / 256, 4), 256, 0, stream>>>(Whh0, Wih1, Whh1, Whhd, wsp);
    init_state<<<ew_blocks, 256, 0, stream>>>(x, h0h, h0l, h1h, h1l, din);

    dim3 blk(256);
    for (int t = 0; t < TOBS; ++t) {
        // gh0 = h0 @ Whh0^T
        GemmOps o1 = {{h0h, h0h}, {h0l, h0l}, {Whh0h, Whh0h}, {Whh0l, Whh0l}, {g0, g0}};
        gemm3<<<dim3(768, 1, 1), blk, 0, stream>>>(o1);
        gru_l0<<<ew_blocks, 256, 0, stream>>>(x, t, Wih0, bih0, bhh0, g0, h0h, h0l);
        // gi1 = h0_new @ Wih1^T ; gh1 = h1 @ Whh1^T (dual via grid.z)
        GemmOps o2 = {{h0h, h1h}, {h0l, h1l}, {Wih1h, Whh1h}, {Wih1l, Whh1l}, {g0, g1}};
        gemm3<<<dim3(768, 1, 2), blk, 0, stream>>>(o2);
        gru_l1<<<ew_blocks, 256, 0, stream>>>(g0, g1, bih1, bhh1, h1h, h1l);
    }
    for (int t = 0; t < TPRED; ++t) {
        // ghd = h1 @ Whhd^T
        GemmOps o3 = {{h1h, h1h}, {h1l, h1l}, {Whhdh, Whhdh}, {Whhdl, Whhdl}, {g0, g0}};
        gemm3<<<dim3(768, 1, 1), blk, 0, stream>>>(o3);
        gru_dec<<<B_SZ, 512, 0, stream>>>(din, Wihd, bihd, bhhd, g0, h1h, h1l,
                                          Wfc, bfc, out, t);
    }
}

// Round 3
// 3355.401 us; speedup vs baseline: 3.8075x; 1.4936x over previous
//
#include <hip/hip_runtime.h>
#include <math.h>

// GRU seq2seq on MI355X. Round 3: 1-term bf16 MFMA GEMM (tolerance probe).
// State h kept fp32 (exact recurrence); bf16 mirror feeds the GEMM. Weights bf16 RNE.
// GEMM: tile 128x96, BK=64, 512 blocks = 2/CU exact, gl16 staging w/ XOR chunk swizzle.

#define B_SZ  4096
#define H     512
#define H3    1536
#define TOBS  30
#define TPRED 60

typedef float f32x4 __attribute__((ext_vector_type(4)));
typedef short s16x8 __attribute__((ext_vector_type(8)));
typedef __bf16 bf16x8 __attribute__((ext_vector_type(8)));

__device__ __forceinline__ float b2f(unsigned short u) {
    unsigned v = (unsigned)u << 16; return __builtin_bit_cast(float, v);
}
__device__ __forceinline__ unsigned short f2b(float f) {  // RNE
    unsigned u = __builtin_bit_cast(unsigned, f);
    return (unsigned short)((u + 0x7FFF + ((u >> 16) & 1)) >> 16);
}

typedef __attribute__((address_space(1))) void gvoid;
typedef __attribute__((address_space(3))) void lvoid;
__device__ __forceinline__ void gl16(const void* g, void* l) {
    __builtin_amdgcn_global_load_lds((gvoid*)g, (lvoid*)l, 16, 0, 0);
}

__device__ __forceinline__ f32x4 mfma_bf16(s16x8 a, s16x8 b, f32x4 c) {
    return __builtin_amdgcn_mfma_f32_16x16x32_bf16(
        __builtin_bit_cast(bf16x8, a), __builtin_bit_cast(bf16x8, b), c, 0, 0, 0);
}

struct GemmOps {
    const unsigned short* A[2];
    const unsigned short* W[2];
    float* C[2];
};

// C[m][n] = sum_k A[m][k]*W[n][k], bf16 in, fp32 out. M=4096 N=1536 K=512.
// Tile 128(m) x 96(n), BK=64. 256 thr = 4 waves (2x2), wave-tile 64x48.
// grid.x = 512 (16 n-tiles x 32 m-tiles) XCD-swizzled; grid.z = operand set.
__global__ __launch_bounds__(256)
void gemm1(GemmOps ops)
{
    const int z = blockIdx.z;
    const unsigned short* __restrict__ A = ops.A[z];
    const unsigned short* __restrict__ W = ops.W[z];
    float* __restrict__ C = ops.C[z];

    // 512 blocks, 8 XCDs, 64 contiguous per XCD (bijective).
    int bid = (int)blockIdx.x;
    int swz = (bid & 7) * 64 + (bid >> 3);
    const int n0 = (swz & 15) * 96;
    const int m0 = (swz >> 4) * 128;

    // row-major [row][64 k] u16; 8 chunks of 16B per row, chunk XOR-swizzled by (row&7).
    __shared__ unsigned short sA[128 * 64];
    __shared__ unsigned short sB[96 * 64];

    const int tid  = threadIdx.x;
    const int lane = tid & 63;
    const int w    = tid >> 6;
    const int wr = w >> 1, wc = w & 1;
    const int lr = lane & 15;
    const int q  = lane >> 4;            // 0..3
    const int wbase = tid & ~63;         // wave-uniform slot base

    f32x4 acc[4][3];
#pragma unroll
    for (int i = 0; i < 4; ++i)
#pragma unroll
        for (int j = 0; j < 3; ++j) acc[i][j] = (f32x4){0.f, 0.f, 0.f, 0.f};

    for (int k0 = 0; k0 < H; k0 += 64) {
        // Stage A: 1024 slots of 16B (4 rounds). slot i: row=i>>3, p=i&7, fetch chunk p^(row&7).
#pragma unroll
        for (int s = 0; s < 4; ++s) {
            int i = s * 256 + tid;
            int row = i >> 3, p = i & 7;
            int c = p ^ (row & 7);
            gl16(A + (size_t)(m0 + row) * H + k0 + c * 8, &sA[(s * 256 + wbase) * 8]);
        }
        // Stage B: 768 slots (3 rounds), 96 rows.
#pragma unroll
        for (int s = 0; s < 3; ++s) {
            int i = s * 256 + tid;
            int row = i >> 3, p = i & 7;
            int c = p ^ (row & 7);
            gl16(W + (size_t)(n0 + row) * H + k0 + c * 8, &sB[(s * 256 + wbase) * 8]);
        }
        __syncthreads();

#pragma unroll
        for (int kk = 0; kk < 64; kk += 32) {
            int qb = (kk >> 3) + q;      // chunk index 0..7
            s16x8 af[4], bf[3];
#pragma unroll
            for (int fi = 0; fi < 4; ++fi) {
                int r = wr * 64 + fi * 16 + lr;
                int pos = qb ^ (r & 7);
                af[fi] = *(const s16x8*)&sA[r * 64 + pos * 8];
            }
#pragma unroll
            for (int fj = 0; fj < 3; ++fj) {
                int r = wc * 48 + fj * 16 + lr;
                int pos = qb ^ (r & 7);
                bf[fj] = *(const s16x8*)&sB[r * 64 + pos * 8];
            }
#pragma unroll
            for (int fi = 0; fi < 4; ++fi)
#pragma unroll
                for (int fj = 0; fj < 3; ++fj)
                    acc[fi][fj] = mfma_bf16(af[fi], bf[fj], acc[fi][fj]);
        }
        __syncthreads();
    }

    // C/D: col = lane&15, row = (lane>>4)*4 + reg
#pragma unroll
    for (int fi = 0; fi < 4; ++fi)
#pragma unroll
        for (int fj = 0; fj < 3; ++fj) {
            int col  = n0 + wc * 48 + fj * 16 + lr;
            int rowb = m0 + wr * 64 + fi * 16 + q * 4;
#pragma unroll
            for (int j = 0; j < 4; ++j)
                C[(size_t)(rowb + j) * H3 + col] = acc[fi][fj][j];
        }
}

// Convert 4 weight matrices (H3 x H fp32) to bf16 (RNE).
__global__ void wprep(const float* __restrict__ s0, const float* __restrict__ s1,
                      const float* __restrict__ s2, const float* __restrict__ s3,
                      unsigned short* __restrict__ d)
{
    int m = blockIdx.y;
    const float* s = (m == 0) ? s0 : (m == 1) ? s1 : (m == 2) ? s2 : s3;
    unsigned short* dm = d + (size_t)m * H3 * H;
    int i = blockIdx.x * 256 + threadIdx.x;
    dm[i] = f2b(s[i]);
}

__global__ void init_state(const float* __restrict__ x,
                           float* __restrict__ hf0, float* __restrict__ hf1,
                           unsigned short* __restrict__ hb0, unsigned short* __restrict__ hb1,
                           float* __restrict__ din)
{
    int idx = blockIdx.x * blockDim.x + threadIdx.x;
    if (idx < B_SZ * H) { hf0[idx] = 0.f; hf1[idx] = 0.f; hb0[idx] = 0; hb1[idx] = 0; }
    if (idx < B_SZ * 2) din[idx] = x[(size_t)(idx >> 1) * (TOBS * 4) + 29 * 4 + (idx & 1)];
}

__device__ __forceinline__ float sigmoidf_(float v) { return 1.f / (1.f + expf(-v)); }

// Layer-0 cell: gi (K=4) inline from x; gh from GEMM buffer. h fp32 + bf16 mirror.
__global__ void gru_l0(const float* __restrict__ x, int t,
                       const float* __restrict__ Wih, const float* __restrict__ bih,
                       const float* __restrict__ bhh, const float* __restrict__ gh,
                       float* __restrict__ hf, unsigned short* __restrict__ hb)
{
    int idx = blockIdx.x * blockDim.x + threadIdx.x;
    int b = idx >> 9, j = idx & (H - 1);
    const float* xb = x + (size_t)b * (TOBS * 4) + t * 4;
    float x0 = xb[0], x1 = xb[1], x2 = xb[2], x3 = xb[3];
    const float* w0 = Wih + (size_t)j * 4;
    const float* w1 = Wih + (size_t)(H + j) * 4;
    const float* w2 = Wih + (size_t)(2 * H + j) * 4;
    float gir = bih[j]     + x0*w0[0] + x1*w0[1] + x2*w0[2] + x3*w0[3];
    float giz = bih[H+j]   + x0*w1[0] + x1*w1[1] + x2*w1[2] + x3*w1[3];
    float gin = bih[2*H+j] + x0*w2[0] + x1*w2[1] + x2*w2[2] + x3*w2[3];
    size_t base = (size_t)b * H3;
    float r  = sigmoidf_(gir + gh[base + j]       + bhh[j]);
    float zg = sigmoidf_(giz + gh[base + H + j]   + bhh[H + j]);
    float n  = tanhf(gin + r * (gh[base + 2*H + j] + bhh[2*H + j]));
    float hn = (1.f - zg) * n + zg * hf[idx];
    hf[idx] = hn;
    hb[idx] = f2b(hn);
}

// Layer-1 cell: gi and gh from GEMM buffers.
__global__ void gru_l1(const float* __restrict__ gi, const float* __restrict__ gh,
                       const float* __restrict__ bih, const float* __restrict__ bhh,
                       float* __restrict__ hf, unsigned short* __restrict__ hb)
{
    int idx = blockIdx.x * blockDim.x + threadIdx.x;
    int b = idx >> 9, j = idx & (H - 1);
    size_t base = (size_t)b * H3;
    float r  = sigmoidf_(gi[base + j]       + bih[j]       + gh[base + j]       + bhh[j]);
    float zg = sigmoidf_(gi[base + H + j]   + bih[H + j]   + gh[base + H + j]   + bhh[H + j]);
    float n  = tanhf(gi[base + 2*H + j] + bih[2*H + j]
                     + r * (gh[base + 2*H + j] + bhh[2*H + j]));
    float hn = (1.f - zg) * n + zg * hf[idx];
    hf[idx] = hn;
    hb[idx] = f2b(hn);
}

// Decoder cell + FC head. One block per batch row, 512 threads = hidden units.
__global__ __launch_bounds__(512)
void gru_dec(float* __restrict__ din, const float* __restrict__ Wih,
             const float* __restrict__ bih, const float* __restrict__ bhh,
             const float* __restrict__ gh,
             float* __restrict__ hf, unsigned short* __restrict__ hb,
             const float* __restrict__ Wfc, const float* __restrict__ bfc,
             float* __restrict__ out, int t)
{
    int b = blockIdx.x, j = threadIdx.x;
    float x0 = din[b * 2 + 0], x1 = din[b * 2 + 1];
    float gir = bih[j]       + x0 * Wih[(size_t)j * 2]         + x1 * Wih[(size_t)j * 2 + 1];
    float giz = bih[H + j]   + x0 * Wih[(size_t)(H + j) * 2]   + x1 * Wih[(size_t)(H + j) * 2 + 1];
    float gin = bih[2*H + j] + x0 * Wih[(size_t)(2*H + j) * 2] + x1 * Wih[(size_t)(2*H + j) * 2 + 1];
    size_t base = (size_t)b * H3;
    float r  = sigmoidf_(gir + gh[base + j]       + bhh[j]);
    float zg = sigmoidf_(giz + gh[base + H + j]   + bhh[H + j]);
    float n  = tanhf(gin + r * (gh[base + 2*H + j] + bhh[2*H + j]));
    int idx = b * H + j;
    float hn = (1.f - zg) * n + zg * hf[idx];
    hf[idx] = hn;
    hb[idx] = f2b(hn);

    float v0 = hn * Wfc[j];
    float v1 = hn * Wfc[H + j];
#pragma unroll
    for (int m = 32; m; m >>= 1) { v0 += __shfl_xor(v0, m); v1 += __shfl_xor(v1, m); }
    __shared__ float red0[8], red1[8];
    int wv = j >> 6, ln = j & 63;
    if (ln == 0) { red0[wv] = v0; red1[wv] = v1; }
    __syncthreads();
    if (j == 0) {
        float p0 = bfc[0], p1 = bfc[1];
#pragma unroll
        for (int wv2 = 0; wv2 < 8; ++wv2) { p0 += red0[wv2]; p1 += red1[wv2]; }
        out[(size_t)b * (TPRED * 2) + t * 2 + 0] = p0;
        out[(size_t)b * (TPRED * 2) + t * 2 + 1] = p1;
        din[b * 2 + 0] = p0;
        din[b * 2 + 1] = p1;
    }
}

extern "C" void kernel_launch(void* const* d_in, const int* in_sizes, int n_in,
                              void* d_out, int out_size, void* d_ws, size_t ws_size,
                              hipStream_t stream)
{
    const float* x    = (const float*)d_in[0];
    const float* Wih0 = (const float*)d_in[1];
    const float* Whh0 = (const float*)d_in[2];
    const float* bih0 = (const float*)d_in[3];
    const float* bhh0 = (const float*)d_in[4];
    const float* Wih1 = (const float*)d_in[5];
    const float* Whh1 = (const float*)d_in[6];
    const float* bih1 = (const float*)d_in[7];
    const float* bhh1 = (const float*)d_in[8];
    const float* Wihd = (const float*)d_in[9];
    const float* Whhd = (const float*)d_in[10];
    const float* bihd = (const float*)d_in[11];
    const float* bhhd = (const float*)d_in[12];
    const float* Wfc  = (const float*)d_in[13];
    const float* bfc  = (const float*)d_in[14];
    float* out = (float*)d_out;

    // workspace: g0,g1 (B*H3 f32) | din | hf0,hf1 (B*H f32) | hb0,hb1 (B*H u16) | W bf16 x4
    char* p = (char*)d_ws;
    float* g0  = (float*)p;  p += (size_t)B_SZ * H3 * 4;
    float* g1  = (float*)p;  p += (size_t)B_SZ * H3 * 4;
    float* din = (float*)p;  p += (size_t)B_SZ * 2 * 4;
    float* hf0 = (float*)p;  p += (size_t)B_SZ * H * 4;
    float* hf1 = (float*)p;  p += (size_t)B_SZ * H * 4;
    unsigned short* hb0 = (unsigned short*)p; p += (size_t)B_SZ * H * 2;
    unsigned short* hb1 = (unsigned short*)p; p += (size_t)B_SZ * H * 2;
    unsigned short* wsp = (unsigned short*)p;
    const size_t WM = (size_t)H3 * H;
    unsigned short* Whh0b = wsp + 0 * WM;
    unsigned short* Wih1b = wsp + 1 * WM;
    unsigned short* Whh1b = wsp + 2 * WM;
    unsigned short* Whhdb = wsp + 3 * WM;

    int ew_blocks = (B_SZ * H) / 256;
    wprep<<<dim3((H3 * H) / 256, 4), 256, 0, stream>>>(Whh0, Wih1, Whh1, Whhd, wsp);
    init_state<<<ew_blocks, 256, 0, stream>>>(x, hf0, hf1, hb0, hb1, din);

    dim3 blk(256);
    for (int t = 0; t < TOBS; ++t) {
        // gh0 = h0 @ Whh0^T
        GemmOps o1 = {{hb0, hb0}, {Whh0b, Whh0b}, {g0, g0}};
        gemm1<<<dim3(512, 1, 1), blk, 0, stream>>>(o1);
        gru_l0<<<ew_blocks, 256, 0, stream>>>(x, t, Wih0, bih0, bhh0, g0, hf0, hb0);
        // gi1 = h0_new @ Wih1^T ; gh1 = h1 @ Whh1^T  (dual via grid.z)
        GemmOps o2 = {{hb0, hb1}, {Wih1b, Whh1b}, {g0, g1}};
        gemm1<<<dim3(512, 1, 2), blk, 0, stream>>>(o2);
        gru_l1<<<ew_blocks, 256, 0, stream>>>(g0, g1, bih1, bhh1, hf1, hb1);
    }
    for (int t = 0; t < TPRED; ++t) {
        // ghd = h1 @ Whhd^T
        GemmOps o3 = {{hb1, hb1}, {Whhdb, Whhdb}, {g0, g0}};
        gemm1<<<dim3(512, 1, 1), blk, 0, stream>>>(o3);
        gru_dec<<<B_SZ, 512, 0, stream>>>(din, Wihd, bihd, bhhd, g0, hf1, hb1,
                                          Wfc, bfc, out, t);
    }
}